// Round 4
// baseline (149.863 us; speedup 1.0000x reference)
//
#include <hip/hip_runtime.h>
#include <hip/hip_bf16.h>

typedef unsigned short u16;
typedef unsigned int u32;
typedef __attribute__((ext_vector_type(8))) short bf16x8;   // 8 bf16 (4 VGPRs)
typedef __attribute__((ext_vector_type(8))) u16 u16x8;
typedef __attribute__((ext_vector_type(4))) u16 u16x4;
typedef __attribute__((ext_vector_type(4))) u32 u32x4;
typedef __attribute__((ext_vector_type(4))) float f32x4;
typedef __attribute__((ext_vector_type(16))) float f32x16;

typedef const __attribute__((address_space(1))) void* gas1_t;
typedef __attribute__((address_space(3))) void* las3_t;

#define MFMA16(a,b,c) __builtin_amdgcn_mfma_f32_16x16x32_bf16((a),(b),(c),0,0,0)
#define MFMA32(a,b,c) __builtin_amdgcn_mfma_f32_32x32x16_bf16((a),(b),(c),0,0,0)

static constexpr int BB = 4, SS = 1024, DD = 1024, HH = 16;

static __device__ __forceinline__ u16 f2b(float x) {
  union { __hip_bfloat16 h; u16 u; } cv;
  cv.h = __float2bfloat16(x);
  return cv.u;
}
static __device__ __forceinline__ u32 pk2(float a, float b) {
  return (u32)f2b(a) | ((u32)f2b(b) << 16);
}

// ---------------- fused fp32 -> bf16 conversion (one launch for all 7 tensors) ----------------
__global__ __launch_bounds__(256) void cvt_all(
    const float* __restrict__ q, const float* __restrict__ k, const float* __restrict__ v,
    const float* __restrict__ wq_, const float* __restrict__ wk_, const float* __restrict__ wv_,
    const float* __restrict__ wp_,
    u16* __restrict__ qb, u16* __restrict__ kb, u16* __restrict__ vb,
    u16* __restrict__ wqb, u16* __restrict__ wkb, u16* __restrict__ wvb, u16* __restrict__ wpb) {
  int bid = blockIdx.x;
  const float* s; u16* d; int off;
  if      (bid < 4096)  { s = q;   d = qb;  off = bid; }
  else if (bid < 8192)  { s = k;   d = kb;  off = bid - 4096; }
  else if (bid < 12288) { s = v;   d = vb;  off = bid - 8192; }
  else if (bid < 13312) { s = wq_; d = wqb; off = bid - 12288; }
  else if (bid < 14336) { s = wk_; d = wkb; off = bid - 13312; }
  else if (bid < 15360) { s = wv_; d = wvb; off = bid - 14336; }
  else                  { s = wp_; d = wpb; off = bid - 15360; }
  int i = (off * 256 + threadIdx.x) * 4;
  float4 val = *(const float4*)(s + i);
  u16x4 r = { f2b(val.x), f2b(val.y), f2b(val.z), f2b(val.w) };
  *(u16x4*)(d + i) = r;
}

// ---------------- GEMM: C[M,N] = A[M,K] * W[N,K]^T  (m97-style 128x128 tile) ----------------
template<typename OT>
__global__ __launch_bounds__(256) void gemm_bt(
    const u16* __restrict__ Abase, const u16* __restrict__ Wbase, OT* __restrict__ Cbase,
    int N, int K, size_t sA, size_t sW, size_t sC) {
  const u16* A = Abase + (size_t)blockIdx.z * sA;
  const u16* W = Wbase + (size_t)blockIdx.z * sW;
  OT* C = Cbase + (size_t)blockIdx.z * sC;

  __shared__ __align__(16) u16 As[128 * 32];
  __shared__ __align__(16) u16 Bs[128 * 32];

  const int tid = threadIdx.x;
  const int lane = tid & 63;
  const int wid = tid >> 6;
  const int g = lane >> 4;
  const int li = lane & 15;
  const int brow = blockIdx.y * 128;
  const int bcol = blockIdx.x * 128;
  const int wr = (wid >> 1) * 64;
  const int wc = (wid & 1) * 64;

  const int srow = tid >> 2;
  const int scol = (tid & 3) * 8;

  f32x4 acc[4][4] = {};

  for (int k0 = 0; k0 < K; k0 += 32) {
#pragma unroll
    for (int c = 0; c < 2; ++c) {
      const u16* ga = A + (size_t)(brow + srow + c * 64) * K + k0 + scol;
      const u16* gw = W + (size_t)(bcol + srow + c * 64) * K + k0 + scol;
      __builtin_amdgcn_global_load_lds((gas1_t)(const void*)ga,
                                       (las3_t)(void*)(As + wid * 512 + c * 2048), 16, 0, 0);
      __builtin_amdgcn_global_load_lds((gas1_t)(const void*)gw,
                                       (las3_t)(void*)(Bs + wid * 512 + c * 2048), 16, 0, 0);
    }
    __syncthreads();

    bf16x8 a[4], b[4];
#pragma unroll
    for (int m = 0; m < 4; ++m)
      a[m] = *(const bf16x8*)&As[(wr + m * 16 + li) * 32 + g * 8];
#pragma unroll
    for (int n = 0; n < 4; ++n)
      b[n] = *(const bf16x8*)&Bs[(wc + n * 16 + li) * 32 + g * 8];
#pragma unroll
    for (int m = 0; m < 4; ++m)
#pragma unroll
      for (int n = 0; n < 4; ++n)
        acc[m][n] = MFMA16(a[m], b[n], acc[m][n]);
    __syncthreads();
  }

#pragma unroll
  for (int m = 0; m < 4; ++m)
#pragma unroll
    for (int n = 0; n < 4; ++n)
#pragma unroll
      for (int j = 0; j < 4; ++j) {
        int r = brow + wr + m * 16 + g * 4 + j;
        int c = bcol + wc + n * 16 + li;
        if constexpr (sizeof(OT) == 2) C[(size_t)r * N + c] = (OT)f2b(acc[m][n][j]);
        else                           C[(size_t)r * N + c] = acc[m][n][j];
      }
}

// ---------------- V transpose: V[b*S+s][h*64+dv] -> Vt[((b*H+h)*64+dv)*S + s] ----------------
__global__ __launch_bounds__(256) void transpose_v(const u16* __restrict__ V, u16* __restrict__ Vt) {
  __shared__ __align__(16) u16 t[64][72];
  const int s0 = blockIdx.x * 64, h = blockIdx.y, b = blockIdx.z;
  const int tid = threadIdx.x;
#pragma unroll
  for (int it = 0; it < 2; ++it) {
    int slot = tid + it * 256;
    int r = slot >> 3, seg = slot & 7;
    *(u16x8*)&t[r][seg * 8] = *(const u16x8*)&V[(size_t)(b * SS + s0 + r) * DD + h * 64 + seg * 8];
  }
  __syncthreads();
#pragma unroll
  for (int it = 0; it < 2; ++it) {
    int slot = tid + it * 256;
    int dv = slot >> 3, seg = slot & 7;
    u16x8 v;
#pragma unroll
    for (int i = 0; i < 8; ++i) v[i] = t[seg * 8 + i][dv];
    *(u16x8*)&Vt[(size_t)((b * HH + h) * 64 + dv) * SS + s0 + seg * 8] = v;
  }
}

// ---------------- fused flash attention: 8 waves, kv-split into two 4-wave groups ----------------
// grid: (S/128, H, B) remapped XCD-chunked; block 512.
// Waves 0-3: kv tiles 0-7; waves 4-7: kv tiles 8-15; same 128 q-rows; fp32 merge at end.
__global__ __launch_bounds__(512) void attn_kernel(
    const u16* __restrict__ Q, const u16* __restrict__ K, const u16* __restrict__ Vt,
    const float* __restrict__ bias, u16* __restrict__ O) {
  // smem: 8 x 8KB kv buffers: [g2*4 + type*2 + cur]  (type 0 = K, 1 = V)
  __shared__ __align__(16) u16 smem[8 * 4096];
  __shared__ float Lf[8][32];

  const int tid = threadIdx.x;
  const int lane = tid & 63;
  const int wid = tid >> 6;         // 0..7
  const int g2 = tid >> 8;          // kv-split group (0: tiles 0-7, 1: tiles 8-15)
  const int wqq = wid & 3;          // q-strip within block
  const int hi = lane >> 5;
  const int ln = lane & 31;
  const u32 swz = (u32)(ln & 7) << 4;

  // XCD-chunked bijective remap (512 blocks, 8 XCDs -> 64-block chunks)
  const int flat = blockIdx.x + (blockIdx.y << 3) + (blockIdx.z << 7);
  const int w = ((flat & 7) << 6) | (flat >> 3);
  const int qt = w & 7, h = (w >> 3) & 15, b = w >> 7;
  const int q0 = qt * 128;
  const int qrow = q0 + wqq * 32 + ln;      // this lane's softmax row

  // Q B-fragments: lane holds Q[qrow][d = dstep*16 + hi*8 + e]
  bf16x8 qf[4];
  {
    const u16* qp = Q + (size_t)(b * SS + qrow) * DD + h * 64 + hi * 8;
#pragma unroll
    for (int d = 0; d < 4; ++d) qf[d] = *(const bf16x8*)(qp + d * 16);
  }

  // staging map within group: 256 threads -> (row sr, 32B chunk)
  const int t8 = tid & 255;
  const int sr = t8 >> 2;
  const int scb = (t8 & 3) * 32;
  const u16* kg = K + (size_t)(b * SS + g2 * 512 + sr) * DD + h * 64 + scb / 2;
  const u16* vg = Vt + (size_t)((b * HH + h) * 64 + sr) * SS + g2 * 512 + scb / 2;
  const u32 wa0 = (u32)sr * 128 + (((u32)scb) ^ ((u32)(sr & 7) << 4));
  const u32 wa1 = (u32)sr * 128 + (((u32)scb + 16) ^ ((u32)(sr & 7) << 4));

  u16x8 kr0, kr1, vr0, vr1;
  kr0 = *(const u16x8*)(kg + 0);
  kr1 = *(const u16x8*)(kg + 8);
  vr0 = *(const u16x8*)(vg + 0);
  vr1 = *(const u16x8*)(vg + 8);
  {
    char* kd = (char*)(smem + (g2 * 4 + 0) * 4096);
    char* vd = (char*)(smem + (g2 * 4 + 2) * 4096);
    *(u16x8*)(kd + wa0) = kr0;
    *(u16x8*)(kd + wa1) = kr1;
    *(u16x8*)(vd + wa0) = vr0;
    *(u16x8*)(vd + wa1) = vr1;
  }
  __syncthreads();

  const float* bp = bias + (size_t)(b * SS + qrow) * SS + g2 * 512 + hi * 4;

  f32x16 o0 = {}, o1 = {};
  float m = -1e30f, lsum = 0.f;
  int cur = 0;

  for (int kt = 0; kt < 8; ++kt) {
    // T14: issue next-tile global loads early
    if (kt < 7) {
      const size_t k1 = (size_t)(kt + 1) * 64;
      kr0 = *(const u16x8*)(kg + k1 * DD + 0);
      kr1 = *(const u16x8*)(kg + k1 * DD + 8);
      vr0 = *(const u16x8*)(vg + k1 + 0);
      vr1 = *(const u16x8*)(vg + k1 + 8);
    }

    // bias: fragment-aligned float4 gathers (row = qrow, lane-local)
    f32x4 bb[2][4];
    {
      const float* bpt = bp + kt * 64;
#pragma unroll
      for (int kb = 0; kb < 2; ++kb)
#pragma unroll
        for (int rq = 0; rq < 4; ++rq)
          bb[kb][rq] = *(const f32x4*)(bpt + kb * 32 + rq * 8);
    }

    // swapped QK^T: s = mfma(K, Q) -> C: col = q = ln, row(k) = (r&3)+8*(r>>2)+4*hi (+32*kb)
    const char* kb_base = (const char*)(smem + (g2 * 4 + 0 + cur) * 4096);
    f32x16 s[2];
    __builtin_amdgcn_s_setprio(1);
#pragma unroll
    for (int kb = 0; kb < 2; ++kb) {
      f32x16 acc = {};
#pragma unroll
      for (int d = 0; d < 4; ++d) {
        bf16x8 kf = *(const bf16x8*)(kb_base + (kb * 32 + ln) * 128 + (((u32)(d * 32 + hi * 16)) ^ swz));
        acc = MFMA32(kf, qf[d], acc);
      }
      s[kb] = acc;
    }
    __builtin_amdgcn_s_setprio(0);

    // scale (D^-0.5 = 1/32) + bias in fp32
#pragma unroll
    for (int kb = 0; kb < 2; ++kb)
#pragma unroll
      for (int rq = 0; rq < 4; ++rq)
#pragma unroll
        for (int c = 0; c < 4; ++c)
          s[kb][rq * 4 + c] = fmaf(s[kb][rq * 4 + c], 0.03125f, bb[kb][rq][c]);

    // in-register row softmax (row is lane-local; only cross-hi shuffle needed)
    float mt = -1e30f;
#pragma unroll
    for (int r = 0; r < 16; ++r) { mt = fmaxf(mt, s[0][r]); mt = fmaxf(mt, s[1][r]); }
    mt = fmaxf(mt, __shfl_xor(mt, 32));

    bool resc = false;
    float fsc = 1.f;
    if (kt == 0) {
      m = mt;
    } else if (__any(mt > m + 8.f)) {   // T13 defer-max
      float mn = fmaxf(m, mt);
      fsc = __expf(m - mn);
      m = mn;
      resc = true;
    }

    float rs = 0.f;
    u32 wv[2][8];
#pragma unroll
    for (int kb = 0; kb < 2; ++kb)
#pragma unroll
      for (int t = 0; t < 8; ++t) {
        float p0 = __expf(s[kb][2 * t] - m);
        float p1 = __expf(s[kb][2 * t + 1] - m);
        rs += p0 + p1;
        wv[kb][t] = pk2(p0, p1);
      }
    rs += __shfl_xor(rs, 32);
    lsum = lsum * fsc + rs;

    if (resc) {  // rescale O: need fsc at q' = crow(r,hi); broadcast via per-warp LDS row
      if (hi == 0) Lf[wid][ln] = fsc;
#pragma unroll
      for (int rq = 0; rq < 4; ++rq) {
        f32x4 fv = *(const f32x4*)&Lf[wid][rq * 8 + hi * 4];
#pragma unroll
        for (int c = 0; c < 4; ++c) { o0[rq * 4 + c] *= fv[c]; o1[rq * 4 + c] *= fv[c]; }
      }
    }

    // PV: rebuild P A-fragments in-register (cross-hi shfl), then mfma(P, V)
    const char* vb_base = (const char*)(smem + (g2 * 4 + 2 + cur) * 4096);
#pragma unroll
    for (int ks = 0; ks < 4; ++ks) {
      const int kb = ks >> 1, i0 = (ks & 1) * 4;
      u32 sA = hi ? wv[kb][i0 + 0] : wv[kb][i0 + 2];
      u32 sB = hi ? wv[kb][i0 + 1] : wv[kb][i0 + 3];
      u32 rA = (u32)__shfl_xor((int)sA, 32);
      u32 rB = (u32)__shfl_xor((int)sB, 32);
      u32 e0 = hi ? rA : wv[kb][i0 + 0];
      u32 e1 = hi ? rB : wv[kb][i0 + 1];
      u32 e2 = hi ? wv[kb][i0 + 2] : rA;
      u32 e3 = hi ? wv[kb][i0 + 3] : rB;
      union { u32x4 u; bf16x8 v; } pc;
      pc.u = (u32x4){e0, e1, e2, e3};
      bf16x8 pa = pc.v;
      __builtin_amdgcn_s_setprio(1);
#pragma unroll
      for (int nv = 0; nv < 2; ++nv) {
        bf16x8 vf = *(const bf16x8*)(vb_base + (nv * 32 + ln) * 128 + (((u32)(ks * 32 + hi * 16)) ^ swz));
        if (nv == 0) o0 = MFMA32(pa, vf, o0);
        else         o1 = MFMA32(pa, vf, o1);
      }
      __builtin_amdgcn_s_setprio(0);
    }

    // write next tile into the other buffer, one barrier per tile
    if (kt < 7) {
      char* kd = (char*)(smem + (g2 * 4 + 0 + (cur ^ 1)) * 4096);
      char* vd = (char*)(smem + (g2 * 4 + 2 + (cur ^ 1)) * 4096);
      *(u16x8*)(kd + wa0) = kr0;
      *(u16x8*)(kd + wa1) = kr1;
      *(u16x8*)(vd + wa0) = vr0;
      *(u16x8*)(vd + wa1) = vr1;
      __syncthreads();
      cur ^= 1;
    }
  }

  // ---- merge the two kv-halves (fp32), then normalize + write (group A only) ----
  // scratch overlays the (dead) kv buffers: [wave 0..3][j 0..33][lane] f32, lane-consecutive
  float* scr = (float*)smem;
  __syncthreads();
  if (wid >= 4) {
    float* sc = scr + ((wid - 4) * 36) * 64 + lane;
#pragma unroll
    for (int j = 0; j < 16; ++j) sc[j * 64] = o0[j];
#pragma unroll
    for (int j = 0; j < 16; ++j) sc[(16 + j) * 64] = o1[j];
    sc[32 * 64] = m;
    sc[33 * 64] = lsum;
  }
  __syncthreads();
  if (wid < 4) {
    float* sc = scr + (wid * 36) * 64 + lane;
    float m_b = sc[32 * 64];
    float l_b = sc[33 * 64];
    float mn = fmaxf(m, m_b);
    float al = __expf(m - mn);
    float be = __expf(m_b - mn);
    lsum = lsum * al + l_b * be;
    if (hi == 0) { Lf[wid][ln] = al; Lf[wid + 4][ln] = be; }
#pragma unroll
    for (int rq = 0; rq < 4; ++rq) {
      f32x4 av = *(const f32x4*)&Lf[wid][rq * 8 + hi * 4];
      f32x4 bv = *(const f32x4*)&Lf[wid + 4][rq * 8 + hi * 4];
#pragma unroll
      for (int c = 0; c < 4; ++c) {
        o0[rq * 4 + c] = o0[rq * 4 + c] * av[c] + sc[(rq * 4 + c) * 64] * bv[c];
        o1[rq * 4 + c] = o1[rq * 4 + c] * av[c] + sc[(16 + rq * 4 + c) * 64] * bv[c];
      }
    }

    float inv = 1.0f / lsum;
    if (hi == 0) Lf[wid][ln] = inv;
#pragma unroll
    for (int rq = 0; rq < 4; ++rq) {
      f32x4 iv = *(const f32x4*)&Lf[wid][rq * 8 + hi * 4];
#pragma unroll
      for (int c = 0; c < 4; ++c) {
        int q = q0 + wid * 32 + rq * 8 + hi * 4 + c;
        u16* op = O + (size_t)(b * SS + q) * DD + h * 64 + ln;
        op[0]  = f2b(o0[rq * 4 + c] * iv[c]);
        op[32] = f2b(o1[rq * 4 + c] * iv[c]);
      }
    }
  }
}

// ---------------- host launch ----------------
extern "C" void kernel_launch(void* const* d_in, const int* in_sizes, int n_in,
                              void* d_out, int out_size, void* d_ws, size_t ws_size,
                              hipStream_t stream) {
  const float* queries = (const float*)d_in[0];
  const float* keys    = (const float*)d_in[1];
  const float* values  = (const float*)d_in[2];
  const float* bias    = (const float*)d_in[3];
  const float* Wq      = (const float*)d_in[4];
  const float* Wk      = (const float*)d_in[5];
  const float* Wv      = (const float*)d_in[6];
  const float* Wp      = (const float*)d_in[7];
  float* out = (float*)d_out;

  char* ws = (char*)d_ws;
  const size_t MB = 1024 * 1024;
  u16* qb  = (u16*)(ws + 0 * MB);
  u16* kb  = (u16*)(ws + 8 * MB);
  u16* vb  = (u16*)(ws + 16 * MB);
  u16* wqb = (u16*)(ws + 24 * MB);
  u16* wkb = (u16*)(ws + 26 * MB);
  u16* wvb = (u16*)(ws + 28 * MB);
  u16* wpb = (u16*)(ws + 30 * MB);
  u16* Qb  = (u16*)(ws + 32 * MB);
  u16* Kb  = (u16*)(ws + 40 * MB);
  u16* Vb  = (u16*)(ws + 48 * MB);
  u16* Vtb = (u16*)(ws + 56 * MB);
  u16* Ob  = (u16*)(ws + 0 * MB);  // reuse qb region (dead after projections)

  const int nAct = BB * SS * DD;  // 4M
  const int nW = DD * DD;         // 1M

  cvt_all<<<dim3(16384), dim3(256), 0, stream>>>(
      queries, keys, values, Wq, Wk, Wv, Wp,
      qb, kb, vb, wqb, wkb, wvb, wpb);

  gemm_bt<u16><<<dim3(8, 32, 3), dim3(256), 0, stream>>>(
      qb, wqb, Qb, DD, DD, (size_t)nAct, (size_t)nW, (size_t)nAct);

  transpose_v<<<dim3(16, 16, 4), dim3(256), 0, stream>>>(Vb, Vtb);

  attn_kernel<<<dim3(8, 16, 4), dim3(512), 0, stream>>>(Qb, Kb, Vtb, bias, Ob);

  gemm_bt<float><<<dim3(8, 32, 1), dim3(256), 0, stream>>>(
      Ob, wpb, out, DD, DD, 0, 0, 0);
}

// Round 5
// 146.352 us; speedup vs baseline: 1.0240x; 1.0240x over previous
//
#include <hip/hip_runtime.h>
#include <hip/hip_bf16.h>

typedef unsigned short u16;
typedef unsigned int u32;
typedef __attribute__((ext_vector_type(8))) short bf16x8;   // 8 bf16 (4 VGPRs)
typedef __attribute__((ext_vector_type(8))) u16 u16x8;
typedef __attribute__((ext_vector_type(8))) _Float16 f16x8;
typedef __attribute__((ext_vector_type(4))) u16 u16x4;
typedef __attribute__((ext_vector_type(4))) u32 u32x4;
typedef __attribute__((ext_vector_type(4))) float f32x4;
typedef __attribute__((ext_vector_type(16))) float f32x16;

typedef const __attribute__((address_space(1))) void* gas1_t;
typedef __attribute__((address_space(3))) void* las3_t;

#define MFMA16(a,b,c) __builtin_amdgcn_mfma_f32_16x16x32_bf16((a),(b),(c),0,0,0)
#define MFMA32(a,b,c) __builtin_amdgcn_mfma_f32_32x32x16_bf16((a),(b),(c),0,0,0)

static constexpr int BB = 4, SS = 1024, DD = 1024, HH = 16;

static __device__ __forceinline__ u16 f2b(float x) {
  union { __hip_bfloat16 h; u16 u; } cv;
  cv.h = __float2bfloat16(x);
  return cv.u;
}
static __device__ __forceinline__ u32 pk2(float a, float b) {
  return (u32)f2b(a) | ((u32)f2b(b) << 16);
}

// ---------------- fused fp32 -> bf16 conversion (one launch for all 7 tensors) ----------------
__global__ __launch_bounds__(256) void cvt_all(
    const float* __restrict__ q, const float* __restrict__ k, const float* __restrict__ v,
    const float* __restrict__ wq_, const float* __restrict__ wk_, const float* __restrict__ wv_,
    const float* __restrict__ wp_,
    u16* __restrict__ qb, u16* __restrict__ kb, u16* __restrict__ vb,
    u16* __restrict__ wqb, u16* __restrict__ wkb, u16* __restrict__ wvb, u16* __restrict__ wpb) {
  int bid = blockIdx.x;
  const float* s; u16* d; int off;
  if      (bid < 4096)  { s = q;   d = qb;  off = bid; }
  else if (bid < 8192)  { s = k;   d = kb;  off = bid - 4096; }
  else if (bid < 12288) { s = v;   d = vb;  off = bid - 8192; }
  else if (bid < 13312) { s = wq_; d = wqb; off = bid - 12288; }
  else if (bid < 14336) { s = wk_; d = wkb; off = bid - 13312; }
  else if (bid < 15360) { s = wv_; d = wvb; off = bid - 14336; }
  else                  { s = wp_; d = wpb; off = bid - 15360; }
  int i = (off * 256 + threadIdx.x) * 4;
  float4 val = *(const float4*)(s + i);
  u16x4 r = { f2b(val.x), f2b(val.y), f2b(val.z), f2b(val.w) };
  *(u16x4*)(d + i) = r;
}

// ---------------- GEMM: C[M,N] = A[M,K] * W[N,K]^T  (m97-style 128x128 tile) ----------------
template<typename OT>
__global__ __launch_bounds__(256) void gemm_bt(
    const u16* __restrict__ Abase, const u16* __restrict__ Wbase, OT* __restrict__ Cbase,
    int N, int K, size_t sA, size_t sW, size_t sC) {
  const u16* A = Abase + (size_t)blockIdx.z * sA;
  const u16* W = Wbase + (size_t)blockIdx.z * sW;
  OT* C = Cbase + (size_t)blockIdx.z * sC;

  __shared__ __align__(16) u16 As[128 * 32];
  __shared__ __align__(16) u16 Bs[128 * 32];

  const int tid = threadIdx.x;
  const int lane = tid & 63;
  const int wid = tid >> 6;
  const int g = lane >> 4;
  const int li = lane & 15;
  const int brow = blockIdx.y * 128;
  const int bcol = blockIdx.x * 128;
  const int wr = (wid >> 1) * 64;
  const int wc = (wid & 1) * 64;

  const int srow = tid >> 2;
  const int scol = (tid & 3) * 8;

  f32x4 acc[4][4] = {};

  for (int k0 = 0; k0 < K; k0 += 32) {
#pragma unroll
    for (int c = 0; c < 2; ++c) {
      const u16* ga = A + (size_t)(brow + srow + c * 64) * K + k0 + scol;
      const u16* gw = W + (size_t)(bcol + srow + c * 64) * K + k0 + scol;
      __builtin_amdgcn_global_load_lds((gas1_t)(const void*)ga,
                                       (las3_t)(void*)(As + wid * 512 + c * 2048), 16, 0, 0);
      __builtin_amdgcn_global_load_lds((gas1_t)(const void*)gw,
                                       (las3_t)(void*)(Bs + wid * 512 + c * 2048), 16, 0, 0);
    }
    __syncthreads();

    bf16x8 a[4], b[4];
#pragma unroll
    for (int m = 0; m < 4; ++m)
      a[m] = *(const bf16x8*)&As[(wr + m * 16 + li) * 32 + g * 8];
#pragma unroll
    for (int n = 0; n < 4; ++n)
      b[n] = *(const bf16x8*)&Bs[(wc + n * 16 + li) * 32 + g * 8];
#pragma unroll
    for (int m = 0; m < 4; ++m)
#pragma unroll
      for (int n = 0; n < 4; ++n)
        acc[m][n] = MFMA16(a[m], b[n], acc[m][n]);
    __syncthreads();
  }

#pragma unroll
  for (int m = 0; m < 4; ++m)
#pragma unroll
    for (int n = 0; n < 4; ++n)
#pragma unroll
      for (int j = 0; j < 4; ++j) {
        int r = brow + wr + m * 16 + g * 4 + j;
        int c = bcol + wc + n * 16 + li;
        if constexpr (sizeof(OT) == 2) C[(size_t)r * N + c] = (OT)f2b(acc[m][n][j]);
        else                           C[(size_t)r * N + c] = acc[m][n][j];
      }
}

// ---------------- V transpose: V[b*S+s][h*64+dv] -> Vt[((b*H+h)*64+dv)*S + s] ----------------
__global__ __launch_bounds__(256) void transpose_v(const u16* __restrict__ V, u16* __restrict__ Vt) {
  __shared__ __align__(16) u16 t[64][72];
  const int s0 = blockIdx.x * 64, h = blockIdx.y, b = blockIdx.z;
  const int tid = threadIdx.x;
#pragma unroll
  for (int it = 0; it < 2; ++it) {
    int slot = tid + it * 256;
    int r = slot >> 3, seg = slot & 7;
    *(u16x8*)&t[r][seg * 8] = *(const u16x8*)&V[(size_t)(b * SS + s0 + r) * DD + h * 64 + seg * 8];
  }
  __syncthreads();
#pragma unroll
  for (int it = 0; it < 2; ++it) {
    int slot = tid + it * 256;
    int dv = slot >> 3, seg = slot & 7;
    u16x8 v;
#pragma unroll
    for (int i = 0; i < 8; ++i) v[i] = t[seg * 8 + i][dv];
    *(u16x8*)&Vt[(size_t)((b * HH + h) * 64 + dv) * SS + s0 + seg * 8] = v;
  }
}

// ---------------- fused flash attention, kv-split ACROSS blocks (flash-decoding) ----------------
// grid: (S/128, H, B*2) remapped XCD-chunked; block 256 = 4 waves, each wave owns 32 q-rows.
// Half g2 processes kv tiles [g2*8, g2*8+8); partials (O fp16, m/l fp32) to scratch.
__global__ __launch_bounds__(256) void attn_kernel(
    const u16* __restrict__ Q, const u16* __restrict__ K, const u16* __restrict__ Vt,
    const float* __restrict__ bias,
    _Float16* __restrict__ Op0, _Float16* __restrict__ Op1,
    float* __restrict__ mp0, float* __restrict__ lp0,
    float* __restrict__ mp1, float* __restrict__ lp1) {
  __shared__ __align__(16) u16 kbuf[2][64 * 64];   // [k][d], XOR-swizzled
  __shared__ __align__(16) u16 vbuf[2][64 * 64];   // [dv][k], XOR-swizzled
  __shared__ float Lf[4][32];

  const int tid = threadIdx.x;
  const int lane = tid & 63;
  const int wq = tid >> 6;
  const int hi = lane >> 5;
  const int ln = lane & 31;
  const u32 swz = (u32)(ln & 7) << 4;

  // bijective XCD-chunked remap: 1024 blocks = 8 XCDs x 128; one (b, half) per XCD
  const int flat = blockIdx.x + (blockIdx.y << 3) + (blockIdx.z << 7);
  const int L = ((flat & 7) << 7) | (flat >> 3);
  const int qt = L & 7, h = (L >> 3) & 15, bz = L >> 7;
  const int b = bz >> 1, g2 = bz & 1;
  const int q0 = qt * 128;
  const int qrow = q0 + wq * 32 + ln;       // this lane's softmax row

  _Float16* Op = g2 ? Op1 : Op0;
  float* mp = g2 ? mp1 : mp0;
  float* lp = g2 ? lp1 : lp0;

  // Q B-fragments: lane holds Q[qrow][d = dstep*16 + hi*8 + e]
  bf16x8 qf[4];
  {
    const u16* qp = Q + (size_t)(b * SS + qrow) * DD + h * 64 + hi * 8;
#pragma unroll
    for (int d = 0; d < 4; ++d) qf[d] = *(const bf16x8*)(qp + d * 16);
  }

  // staging map: thread -> (row sr, 32B chunk); kv rows offset by g2*512
  const int sr = tid >> 2;
  const int scb = (tid & 3) * 32;
  const u16* kg = K + (size_t)(b * SS + g2 * 512 + sr) * DD + h * 64 + scb / 2;
  const u16* vg = Vt + (size_t)((b * HH + h) * 64 + sr) * SS + g2 * 512 + scb / 2;
  const u32 wa0 = (u32)sr * 128 + (((u32)scb) ^ ((u32)(sr & 7) << 4));
  const u32 wa1 = (u32)sr * 128 + (((u32)scb + 16) ^ ((u32)(sr & 7) << 4));

  u16x8 kr0, kr1, vr0, vr1;
  kr0 = *(const u16x8*)(kg + 0);
  kr1 = *(const u16x8*)(kg + 8);
  vr0 = *(const u16x8*)(vg + 0);
  vr1 = *(const u16x8*)(vg + 8);
  *(u16x8*)((char*)kbuf[0] + wa0) = kr0;
  *(u16x8*)((char*)kbuf[0] + wa1) = kr1;
  *(u16x8*)((char*)vbuf[0] + wa0) = vr0;
  *(u16x8*)((char*)vbuf[0] + wa1) = vr1;
  __syncthreads();

  const float* bp = bias + (size_t)(b * SS + qrow) * SS + g2 * 512 + hi * 4;

  f32x16 o0 = {}, o1 = {};
  float m = -1e30f, lsum = 0.f;
  int cur = 0;

  for (int kt = 0; kt < 8; ++kt) {
    // T14: issue next-tile global loads early (consumed by LDS writes after compute)
    if (kt < 7) {
      const size_t k1 = (size_t)(kt + 1) * 64;
      kr0 = *(const u16x8*)(kg + k1 * DD + 0);
      kr1 = *(const u16x8*)(kg + k1 * DD + 8);
      vr0 = *(const u16x8*)(vg + k1 + 0);
      vr1 = *(const u16x8*)(vg + k1 + 8);
    }

    // bias: fragment-aligned float4 gathers (row = qrow, lane-local)
    f32x4 bb[2][4];
    {
      const float* bpt = bp + kt * 64;
#pragma unroll
      for (int kb = 0; kb < 2; ++kb)
#pragma unroll
        for (int rq = 0; rq < 4; ++rq)
          bb[kb][rq] = *(const f32x4*)(bpt + kb * 32 + rq * 8);
    }

    // swapped QK^T: s = mfma(K, Q) -> C: col = q = ln, row(k) = (r&3)+8*(r>>2)+4*hi (+32*kb)
    const char* kb_base = (const char*)kbuf[cur];
    f32x16 s[2];
#pragma unroll
    for (int kb = 0; kb < 2; ++kb) {
      f32x16 acc = {};
#pragma unroll
      for (int d = 0; d < 4; ++d) {
        bf16x8 kf = *(const bf16x8*)(kb_base + (kb * 32 + ln) * 128 + (((u32)(d * 32 + hi * 16)) ^ swz));
        acc = MFMA32(kf, qf[d], acc);
      }
      s[kb] = acc;
    }
    // scale (D^-0.5 = 1/32) + bias in fp32
#pragma unroll
    for (int kb = 0; kb < 2; ++kb)
#pragma unroll
      for (int rq = 0; rq < 4; ++rq)
#pragma unroll
        for (int c = 0; c < 4; ++c)
          s[kb][rq * 4 + c] = fmaf(s[kb][rq * 4 + c], 0.03125f, bb[kb][rq][c]);

    // in-register row softmax (row is lane-local; only cross-hi shuffle needed)
    float mt = -1e30f;
#pragma unroll
    for (int r = 0; r < 16; ++r) { mt = fmaxf(mt, s[0][r]); mt = fmaxf(mt, s[1][r]); }
    mt = fmaxf(mt, __shfl_xor(mt, 32));

    bool resc = false;
    float fsc = 1.f;
    if (kt == 0) {
      m = mt;
    } else if (__any(mt > m + 8.f)) {   // T13 defer-max
      float mn = fmaxf(m, mt);
      fsc = __expf(m - mn);
      m = mn;
      resc = true;
    }

    float rs = 0.f;
    u32 wv[2][8];
#pragma unroll
    for (int kb = 0; kb < 2; ++kb)
#pragma unroll
      for (int t = 0; t < 8; ++t) {
        float p0 = __expf(s[kb][2 * t] - m);
        float p1 = __expf(s[kb][2 * t + 1] - m);
        rs += p0 + p1;
        wv[kb][t] = pk2(p0, p1);
      }
    rs += __shfl_xor(rs, 32);
    lsum = lsum * fsc + rs;

    if (resc) {  // rescale O: need fsc at q' = crow(r,hi); broadcast via per-warp LDS row
      if (hi == 0) Lf[wq][ln] = fsc;
#pragma unroll
      for (int rq = 0; rq < 4; ++rq) {
        f32x4 fv = *(const f32x4*)&Lf[wq][rq * 8 + hi * 4];
#pragma unroll
        for (int c = 0; c < 4; ++c) { o0[rq * 4 + c] *= fv[c]; o1[rq * 4 + c] *= fv[c]; }
      }
    }

    // PV: rebuild P A-fragments in-register (cross-hi shfl), then mfma(P, V)
    const char* vb_base = (const char*)vbuf[cur];
#pragma unroll
    for (int ks = 0; ks < 4; ++ks) {
      const int kb = ks >> 1, i0 = (ks & 1) * 4;
      u32 sA = hi ? wv[kb][i0 + 0] : wv[kb][i0 + 2];
      u32 sB = hi ? wv[kb][i0 + 1] : wv[kb][i0 + 3];
      u32 rA = (u32)__shfl_xor((int)sA, 32);
      u32 rB = (u32)__shfl_xor((int)sB, 32);
      u32 e0 = hi ? rA : wv[kb][i0 + 0];
      u32 e1 = hi ? rB : wv[kb][i0 + 1];
      u32 e2 = hi ? wv[kb][i0 + 2] : rA;
      u32 e3 = hi ? wv[kb][i0 + 3] : rB;
      union { u32x4 u; bf16x8 v; } pc;
      pc.u = (u32x4){e0, e1, e2, e3};
      bf16x8 pa = pc.v;
#pragma unroll
      for (int nv = 0; nv < 2; ++nv) {
        bf16x8 vf = *(const bf16x8*)(vb_base + (nv * 32 + ln) * 128 + (((u32)(ks * 32 + hi * 16)) ^ swz));
        if (nv == 0) o0 = MFMA32(pa, vf, o0);
        else         o1 = MFMA32(pa, vf, o1);
      }
    }

    // write next tile into the other buffer, one barrier per tile
    if (kt < 7) {
      char* kd = (char*)kbuf[cur ^ 1];
      char* vd = (char*)vbuf[cur ^ 1];
      *(u16x8*)(kd + wa0) = kr0;
      *(u16x8*)(kd + wa1) = kr1;
      *(u16x8*)(vd + wa0) = vr0;
      *(u16x8*)(vd + wa1) = vr1;
      __syncthreads();
      cur ^= 1;
    }
  }

  // epilogue: write UNNORMALIZED partial O (fp16) + m/l (fp32) for this kv-half
  const size_t rbase = (size_t)(b * HH + h) * SS;
  if (hi == 0) {
    mp[rbase + qrow] = m;
    lp[rbase + qrow] = lsum;
  }
#pragma unroll
  for (int rq = 0; rq < 4; ++rq) {
#pragma unroll
    for (int c = 0; c < 4; ++c) {
      int q = q0 + wq * 32 + rq * 8 + hi * 4 + c;
      _Float16* op = Op + (rbase + q) * 64 + ln;
      op[0]  = (_Float16)o0[rq * 4 + c];
      op[32] = (_Float16)o1[rq * 4 + c];
    }
  }
}

// ---------------- merge two kv-halves: O = (O0*e0 + O1*e1) / (l0*e0 + l1*e1) ----------------
// grid: 2048 x 256; 8 threads per row (8 dv each); writes bf16 Ob in [B*S, D] head-interleaved.
__global__ __launch_bounds__(256) void merge_kernel(
    const _Float16* __restrict__ Op0, const _Float16* __restrict__ Op1,
    const float* __restrict__ mp0, const float* __restrict__ lp0,
    const float* __restrict__ mp1, const float* __restrict__ lp1,
    u16* __restrict__ Ob) {
  const int tid = threadIdx.x;
  const int row = blockIdx.x * 32 + (tid >> 3);     // (b*H + h)*S + q
  const int dvg = (tid & 7) * 8;
  float m0 = mp0[row], m1 = mp1[row];
  float l0 = lp0[row], l1 = lp1[row];
  float mn = fmaxf(m0, m1);
  float e0 = __expf(m0 - mn), e1 = __expf(m1 - mn);
  float inv = 1.0f / (l0 * e0 + l1 * e1);
  float f0 = e0 * inv, f1 = e1 * inv;
  f16x8 p0 = *(const f16x8*)(Op0 + (size_t)row * 64 + dvg);
  f16x8 p1 = *(const f16x8*)(Op1 + (size_t)row * 64 + dvg);
  const int b = row >> 14, h = (row >> 10) & 15, q = row & 1023;
  u16* dst = Ob + (size_t)(b * SS + q) * DD + h * 64 + dvg;
  u16x8 r;
#pragma unroll
  for (int j = 0; j < 8; ++j)
    r[j] = f2b((float)p0[j] * f0 + (float)p1[j] * f1);
  *(u16x8*)dst = r;
}

// ---------------- host launch ----------------
extern "C" void kernel_launch(void* const* d_in, const int* in_sizes, int n_in,
                              void* d_out, int out_size, void* d_ws, size_t ws_size,
                              hipStream_t stream) {
  const float* queries = (const float*)d_in[0];
  const float* keys    = (const float*)d_in[1];
  const float* values  = (const float*)d_in[2];
  const float* bias    = (const float*)d_in[3];
  const float* Wq      = (const float*)d_in[4];
  const float* Wk      = (const float*)d_in[5];
  const float* Wv      = (const float*)d_in[6];
  const float* Wp      = (const float*)d_in[7];
  float* out = (float*)d_out;

  char* ws = (char*)d_ws;
  const size_t MB = 1024 * 1024;
  u16* qb  = (u16*)(ws + 0 * MB);
  u16* kb  = (u16*)(ws + 8 * MB);
  u16* vb  = (u16*)(ws + 16 * MB);
  u16* wqb = (u16*)(ws + 24 * MB);
  u16* wkb = (u16*)(ws + 26 * MB);
  u16* wvb = (u16*)(ws + 28 * MB);
  u16* wpb = (u16*)(ws + 30 * MB);
  u16* Qb  = (u16*)(ws + 32 * MB);
  u16* Kb  = (u16*)(ws + 40 * MB);
  u16* Vb  = (u16*)(ws + 48 * MB);
  u16* Vtb = (u16*)(ws + 56 * MB);
  // attn partials overlay regions dead after the QKV GEMM / transpose:
  _Float16* Op0 = (_Float16*)(ws + 8 * MB);    // 8.39 MB over kb(+vb head)
  _Float16* Op1 = (_Float16*)(ws + 17 * MB);   // 8.39 MB over vb tail + wqb
  float* mp0 = (float*)(ws + 26 * MB);         // 0.25 MB each, over wkb
  float* lp0 = (float*)(ws + 26 * MB + 256 * 1024);
  float* mp1 = (float*)(ws + 26 * MB + 512 * 1024);
  float* lp1 = (float*)(ws + 26 * MB + 768 * 1024);
  u16* Ob  = (u16*)(ws + 0 * MB);  // merged O over qb (dead after projections)

  const int nAct = BB * SS * DD;  // 4M
  const int nW = DD * DD;         // 1M

  cvt_all<<<dim3(16384), dim3(256), 0, stream>>>(
      queries, keys, values, Wq, Wk, Wv, Wp,
      qb, kb, vb, wqb, wkb, wvb, wpb);

  gemm_bt<u16><<<dim3(8, 32, 3), dim3(256), 0, stream>>>(
      qb, wqb, Qb, DD, DD, (size_t)nAct, (size_t)nW, (size_t)nAct);

  transpose_v<<<dim3(16, 16, 4), dim3(256), 0, stream>>>(Vb, Vtb);

  attn_kernel<<<dim3(8, 16, 8), dim3(256), 0, stream>>>(
      Qb, Kb, Vtb, bias, Op0, Op1, mp0, lp0, mp1, lp1);

  merge_kernel<<<dim3(2048), dim3(256), 0, stream>>>(
      Op0, Op1, mp0, lp0, mp1, lp1, Ob);

  gemm_bt<float><<<dim3(8, 32, 1), dim3(256), 0, stream>>>(
      Ob, wpb, out, DD, DD, 0, 0, 0);
}

// Round 6
// 134.482 us; speedup vs baseline: 1.1144x; 1.0883x over previous
//
#include <hip/hip_runtime.h>
#include <hip/hip_bf16.h>

typedef unsigned short u16;
typedef unsigned int u32;
typedef __attribute__((ext_vector_type(8))) short bf16x8;   // 8 bf16 (4 VGPRs)
typedef __attribute__((ext_vector_type(8))) u16 u16x8;
typedef __attribute__((ext_vector_type(4))) u16 u16x4;
typedef __attribute__((ext_vector_type(4))) u32 u32x4;
typedef __attribute__((ext_vector_type(4))) float f32x4;
typedef __attribute__((ext_vector_type(16))) float f32x16;

typedef const __attribute__((address_space(1))) void* gas1_t;
typedef __attribute__((address_space(3))) void* las3_t;

#define MFMA16(a,b,c) __builtin_amdgcn_mfma_f32_16x16x32_bf16((a),(b),(c),0,0,0)
#define MFMA32(a,b,c) __builtin_amdgcn_mfma_f32_32x32x16_bf16((a),(b),(c),0,0,0)

static constexpr int BB = 4, SS = 1024, DD = 1024, HH = 16;

static __device__ __forceinline__ u16 f2b(float x) {
  union { __hip_bfloat16 h; u16 u; } cv;
  cv.h = __float2bfloat16(x);
  return cv.u;
}
static __device__ __forceinline__ u32 pk2(float a, float b) {
  return (u32)f2b(a) | ((u32)f2b(b) << 16);
}

// ---------------- fused fp32 -> bf16 conversion (one launch for all 7 tensors) ----------------
__global__ __launch_bounds__(256) void cvt_all(
    const float* __restrict__ q, const float* __restrict__ k, const float* __restrict__ v,
    const float* __restrict__ wq_, const float* __restrict__ wk_, const float* __restrict__ wv_,
    const float* __restrict__ wp_,
    u16* __restrict__ qb, u16* __restrict__ kb, u16* __restrict__ vb,
    u16* __restrict__ wqb, u16* __restrict__ wkb, u16* __restrict__ wvb, u16* __restrict__ wpb) {
  int bid = blockIdx.x;
  const float* s; u16* d; int off;
  if      (bid < 4096)  { s = q;   d = qb;  off = bid; }
  else if (bid < 8192)  { s = k;   d = kb;  off = bid - 4096; }
  else if (bid < 12288) { s = v;   d = vb;  off = bid - 8192; }
  else if (bid < 13312) { s = wq_; d = wqb; off = bid - 12288; }
  else if (bid < 14336) { s = wk_; d = wkb; off = bid - 13312; }
  else if (bid < 15360) { s = wv_; d = wvb; off = bid - 14336; }
  else                  { s = wp_; d = wpb; off = bid - 15360; }
  int i = (off * 256 + threadIdx.x) * 4;
  float4 val = *(const float4*)(s + i);
  u16x4 r = { f2b(val.x), f2b(val.y), f2b(val.z), f2b(val.w) };
  *(u16x4*)(d + i) = r;
}

// ---------------- GEMM: C[M,N] = A[M,K] * W[N,K]^T  (m97-style 128x128 tile) ----------------
template<typename OT>
__global__ __launch_bounds__(256) void gemm_bt(
    const u16* __restrict__ Abase, const u16* __restrict__ Wbase, OT* __restrict__ Cbase,
    int N, int K, size_t sA, size_t sW, size_t sC) {
  const u16* A = Abase + (size_t)blockIdx.z * sA;
  const u16* W = Wbase + (size_t)blockIdx.z * sW;
  OT* C = Cbase + (size_t)blockIdx.z * sC;

  __shared__ __align__(16) u16 As[128 * 32];
  __shared__ __align__(16) u16 Bs[128 * 32];

  const int tid = threadIdx.x;
  const int lane = tid & 63;
  const int wid = tid >> 6;
  const int g = lane >> 4;
  const int li = lane & 15;
  const int brow = blockIdx.y * 128;
  const int bcol = blockIdx.x * 128;
  const int wr = (wid >> 1) * 64;
  const int wc = (wid & 1) * 64;

  const int srow = tid >> 2;
  const int scol = (tid & 3) * 8;

  f32x4 acc[4][4] = {};

  for (int k0 = 0; k0 < K; k0 += 32) {
#pragma unroll
    for (int c = 0; c < 2; ++c) {
      const u16* ga = A + (size_t)(brow + srow + c * 64) * K + k0 + scol;
      const u16* gw = W + (size_t)(bcol + srow + c * 64) * K + k0 + scol;
      __builtin_amdgcn_global_load_lds((gas1_t)(const void*)ga,
                                       (las3_t)(void*)(As + wid * 512 + c * 2048), 16, 0, 0);
      __builtin_amdgcn_global_load_lds((gas1_t)(const void*)gw,
                                       (las3_t)(void*)(Bs + wid * 512 + c * 2048), 16, 0, 0);
    }
    __syncthreads();

    bf16x8 a[4], b[4];
#pragma unroll
    for (int m = 0; m < 4; ++m)
      a[m] = *(const bf16x8*)&As[(wr + m * 16 + li) * 32 + g * 8];
#pragma unroll
    for (int n = 0; n < 4; ++n)
      b[n] = *(const bf16x8*)&Bs[(wc + n * 16 + li) * 32 + g * 8];
#pragma unroll
    for (int m = 0; m < 4; ++m)
#pragma unroll
      for (int n = 0; n < 4; ++n)
        acc[m][n] = MFMA16(a[m], b[n], acc[m][n]);
    __syncthreads();
  }

#pragma unroll
  for (int m = 0; m < 4; ++m)
#pragma unroll
    for (int n = 0; n < 4; ++n)
#pragma unroll
      for (int j = 0; j < 4; ++j) {
        int r = brow + wr + m * 16 + g * 4 + j;
        int c = bcol + wc + n * 16 + li;
        if constexpr (sizeof(OT) == 2) C[(size_t)r * N + c] = (OT)f2b(acc[m][n][j]);
        else                           C[(size_t)r * N + c] = acc[m][n][j];
      }
}

// ---------------- V transpose: V[b*S+s][h*64+dv] -> Vt[((b*H+h)*64+dv)*S + s] ----------------
__global__ __launch_bounds__(256) void transpose_v(const u16* __restrict__ V, u16* __restrict__ Vt) {
  __shared__ __align__(16) u16 t[64][72];
  const int s0 = blockIdx.x * 64, h = blockIdx.y, b = blockIdx.z;
  const int tid = threadIdx.x;
#pragma unroll
  for (int it = 0; it < 2; ++it) {
    int slot = tid + it * 256;
    int r = slot >> 3, seg = slot & 7;
    *(u16x8*)&t[r][seg * 8] = *(const u16x8*)&V[(size_t)(b * SS + s0 + r) * DD + h * 64 + seg * 8];
  }
  __syncthreads();
#pragma unroll
  for (int it = 0; it < 2; ++it) {
    int slot = tid + it * 256;
    int dv = slot >> 3, seg = slot & 7;
    u16x8 v;
#pragma unroll
    for (int i = 0; i < 8; ++i) v[i] = t[seg * 8 + i][dv];
    *(u16x8*)&Vt[(size_t)((b * HH + h) * 64 + dv) * SS + s0 + seg * 8] = v;
  }
}

// ---------------- fused flash attention (r2 structure + LDS-staged bias) ----------------
// grid: (S/128, H, B) XCD-remapped; block 256 = 4 waves, each wave owns 32 q-rows (q = lane&31).
// Bias tile (128q x 64k fp32, 32 KB) staged per kt via global_load_lds with source-swizzled
// granules (phys = logical ^ (qq&15)); consumed as swizzled ds_read_b128. Kills the
// 32-line/instr gathers that saturated the TA pipe.
__global__ __launch_bounds__(256) void attn_kernel(
    const u16* __restrict__ Q, const u16* __restrict__ K, const u16* __restrict__ Vt,
    const float* __restrict__ bias, u16* __restrict__ O) {
  __shared__ __align__(16) u16 kbuf[2][64 * 64];   // [k][d], XOR-swizzled      (16 KB)
  __shared__ __align__(16) u16 vbuf[2][64 * 64];   // [dv][k], XOR-swizzled     (16 KB)
  __shared__ __align__(16) float bbuf[8192];       // bias tile [qq][g^qq&15]   (32 KB)

  const int tid = threadIdx.x;
  const int lane = tid & 63;
  const int wq = tid >> 6;
  const int hi = lane >> 5;
  const int ln = lane & 31;
  const u32 swz = (u32)(ln & 7) << 4;

  // bijective XCD-chunked remap: 512 blocks = 8 XCDs x 64
  const int flat = blockIdx.x + (blockIdx.y << 3) + (blockIdx.z << 7);
  const int L = ((flat & 7) << 6) | (flat >> 3);
  const int qt = L & 7, h = (L >> 3) & 15, b = L >> 7;
  const int q0 = qt * 128;
  const int qrow = q0 + wq * 32 + ln;       // this lane's softmax row

  // Q B-fragments: lane holds Q[qrow][d = dstep*16 + hi*8 + e]
  bf16x8 qf[4];
  {
    const u16* qp = Q + (size_t)(b * SS + qrow) * DD + h * 64 + hi * 8;
#pragma unroll
    for (int d = 0; d < 4; ++d) qf[d] = *(const bf16x8*)(qp + d * 16);
  }

  // K/V staging map: thread -> (row sr, 32B chunk)
  const int sr = tid >> 2;
  const int scb = (tid & 3) * 32;
  const u16* kg = K + (size_t)(b * SS + sr) * DD + h * 64 + scb / 2;
  const u16* vg = Vt + (size_t)((b * HH + h) * 64 + sr) * SS + scb / 2;
  const u32 wa0 = (u32)sr * 128 + (((u32)scb) ^ ((u32)(sr & 7) << 4));
  const u32 wa1 = (u32)sr * 128 + (((u32)scb + 16) ^ ((u32)(sr & 7) << 4));

  // bias staging: thread covers rows qq = i*16 + (tid>>4), swizzled granule (invariant in i)
  const int brow_ = tid >> 4;                       // 0..15
  const int bgl = (tid & 15) ^ (brow_ & 15);        // logical granule for this thread
  const float* bsrc = bias + (size_t)(b * SS + q0 + brow_) * SS + bgl * 4;
  char* bdst = (char*)bbuf + wq * 1024;             // wave-uniform; HW adds lane*16

  // bias read addresses (fixed all kernel): element (kb,rq,c): k = kb*32+rq*8+4hi+c
  // LDS byte = qq*256 + ((kb*8+rq*2+hi) ^ (qq&15))*16
  const int qq = wq * 32 + ln;
  const char* bb_base = (const char*)bbuf + qq * 256;
  int baddr[2][4];
#pragma unroll
  for (int kb = 0; kb < 2; ++kb)
#pragma unroll
    for (int rq = 0; rq < 4; ++rq)
      baddr[kb][rq] = ((kb * 8 + rq * 2 + hi) ^ (qq & 15)) << 4;

  // initial K/V tile
  u16x8 kr0, kr1, vr0, vr1;
  kr0 = *(const u16x8*)(kg + 0);
  kr1 = *(const u16x8*)(kg + 8);
  vr0 = *(const u16x8*)(vg + 0);
  vr1 = *(const u16x8*)(vg + 8);
  *(u16x8*)((char*)kbuf[0] + wa0) = kr0;
  *(u16x8*)((char*)kbuf[0] + wa1) = kr1;
  *(u16x8*)((char*)vbuf[0] + wa0) = vr0;
  *(u16x8*)((char*)vbuf[0] + wa1) = vr1;
  __syncthreads();

  f32x16 o0 = {}, o1 = {};
  float m = -1e30f, lsum = 0.f;
  int cur = 0;

  for (int kt = 0; kt < 16; ++kt) {
    // 1. stage bias[kt] -> bbuf (8 x global_load_lds dwordx4, coalesced, pre-swizzled source)
    {
      const float* bs = bsrc + kt * 64;
#pragma unroll
      for (int i = 0; i < 8; ++i)
        __builtin_amdgcn_global_load_lds((gas1_t)(const void*)(bs + i * 16384),
                                         (las3_t)(void*)(bdst + i * 4096), 16, 0, 0);
    }
    // 2. prefetch next K/V tile into regs
    if (kt < 15) {
      const size_t k1 = (size_t)(kt + 1) * 64;
      kr0 = *(const u16x8*)(kg + k1 * DD + 0);
      kr1 = *(const u16x8*)(kg + k1 * DD + 8);
      vr0 = *(const u16x8*)(vg + k1 + 0);
      vr1 = *(const u16x8*)(vg + k1 + 8);
    }

    // 3. swapped QK^T: s = mfma(K, Q) -> C: col = q = ln, row(k) = (r&3)+8*(r>>2)+4*hi (+32*kb)
    const char* kb_base = (const char*)kbuf[cur];
    f32x16 s[2];
#pragma unroll
    for (int kb = 0; kb < 2; ++kb) {
      f32x16 acc = {};
#pragma unroll
      for (int d = 0; d < 4; ++d) {
        bf16x8 kf = *(const bf16x8*)(kb_base + (kb * 32 + ln) * 128 + (((u32)(d * 32 + hi * 16)) ^ swz));
        acc = MFMA32(kf, qf[d], acc);
      }
      s[kb] = acc;
    }

    // 4. bias tile visible to all waves
    __syncthreads();

    // 5. scale (D^-0.5 = 1/32) + bias (LDS, swizzled b128 reads) in fp32
#pragma unroll
    for (int kb = 0; kb < 2; ++kb)
#pragma unroll
      for (int rq = 0; rq < 4; ++rq) {
        f32x4 bbv = *(const f32x4*)(bb_base + baddr[kb][rq]);
#pragma unroll
        for (int c = 0; c < 4; ++c)
          s[kb][rq * 4 + c] = fmaf(s[kb][rq * 4 + c], 0.03125f, bbv[c]);
      }

    // in-register row softmax (row is lane-local; only cross-hi shuffle needed)
    float mt = -1e30f;
#pragma unroll
    for (int r = 0; r < 16; ++r) { mt = fmaxf(mt, s[0][r]); mt = fmaxf(mt, s[1][r]); }
    mt = fmaxf(mt, __shfl_xor(mt, 32));

    bool resc = false;
    float fsc = 1.f;
    if (kt == 0) {
      m = mt;
    } else if (__any(mt > m + 8.f)) {   // T13 defer-max
      float mn = fmaxf(m, mt);
      fsc = __expf(m - mn);
      m = mn;
      resc = true;
    }

    float rs = 0.f;
    u32 wv[2][8];
#pragma unroll
    for (int kb = 0; kb < 2; ++kb)
#pragma unroll
      for (int t = 0; t < 8; ++t) {
        float p0 = __expf(s[kb][2 * t] - m);
        float p1 = __expf(s[kb][2 * t + 1] - m);
        rs += p0 + p1;
        wv[kb][t] = pk2(p0, p1);
      }
    rs += __shfl_xor(rs, 32);
    lsum = lsum * fsc + rs;

    if (resc) {  // rescale O at q' = crow(j,hi), factor fetched via lane broadcast
#pragma unroll
      for (int j = 0; j < 16; ++j) {
        float fv = __shfl(fsc, (j & 3) + 8 * (j >> 2) + 4 * hi);
        o0[j] *= fv; o1[j] *= fv;
      }
    }

    // 6. PV: rebuild P A-fragments in-register (cross-hi shfl), then mfma(P, V)
    const char* vb_base = (const char*)vbuf[cur];
#pragma unroll
    for (int ks = 0; ks < 4; ++ks) {
      const int kb = ks >> 1, i0 = (ks & 1) * 4;
      u32 sA = hi ? wv[kb][i0 + 0] : wv[kb][i0 + 2];
      u32 sB = hi ? wv[kb][i0 + 1] : wv[kb][i0 + 3];
      u32 rA = (u32)__shfl_xor((int)sA, 32);
      u32 rB = (u32)__shfl_xor((int)sB, 32);
      u32 e0 = hi ? rA : wv[kb][i0 + 0];
      u32 e1 = hi ? rB : wv[kb][i0 + 1];
      u32 e2 = hi ? wv[kb][i0 + 2] : rA;
      u32 e3 = hi ? wv[kb][i0 + 3] : rB;
      union { u32x4 u; bf16x8 v; } pc;
      pc.u = (u32x4){e0, e1, e2, e3};
      bf16x8 pa = pc.v;
#pragma unroll
      for (int nv = 0; nv < 2; ++nv) {
        bf16x8 vf = *(const bf16x8*)(vb_base + (nv * 32 + ln) * 128 + (((u32)(ks * 32 + hi * 16)) ^ swz));
        if (nv == 0) o0 = MFMA32(pa, vf, o0);
        else         o1 = MFMA32(pa, vf, o1);
      }
    }

    // 7. write next K/V tile into the other buffer; 8. barrier
    if (kt < 15) {
      char* kd = (char*)kbuf[cur ^ 1];
      char* vd = (char*)vbuf[cur ^ 1];
      *(u16x8*)(kd + wa0) = kr0;
      *(u16x8*)(kd + wa1) = kr1;
      *(u16x8*)(vd + wa0) = vr0;
      *(u16x8*)(vd + wa1) = vr1;
    }
    __syncthreads();
    cur ^= 1;
  }

  // epilogue: normalize (1/l broadcast via shfl) + write O (bf16)
  float inv = 1.0f / lsum;
#pragma unroll
  for (int j = 0; j < 16; ++j) {
    float iv = __shfl(inv, (j & 3) + 8 * (j >> 2) + 4 * hi);
    int q = q0 + wq * 32 + (j & 3) + 8 * (j >> 2) + 4 * hi;
    u16* op = O + (size_t)(b * SS + q) * DD + h * 64 + ln;
    op[0]  = f2b(o0[j] * iv);
    op[32] = f2b(o1[j] * iv);
  }
}

// ---------------- host launch ----------------
extern "C" void kernel_launch(void* const* d_in, const int* in_sizes, int n_in,
                              void* d_out, int out_size, void* d_ws, size_t ws_size,
                              hipStream_t stream) {
  const float* queries = (const float*)d_in[0];
  const float* keys    = (const float*)d_in[1];
  const float* values  = (const float*)d_in[2];
  const float* bias    = (const float*)d_in[3];
  const float* Wq      = (const float*)d_in[4];
  const float* Wk      = (const float*)d_in[5];
  const float* Wv      = (const float*)d_in[6];
  const float* Wp      = (const float*)d_in[7];
  float* out = (float*)d_out;

  char* ws = (char*)d_ws;
  const size_t MB = 1024 * 1024;
  u16* qb  = (u16*)(ws + 0 * MB);
  u16* kb  = (u16*)(ws + 8 * MB);
  u16* vb  = (u16*)(ws + 16 * MB);
  u16* wqb = (u16*)(ws + 24 * MB);
  u16* wkb = (u16*)(ws + 26 * MB);
  u16* wvb = (u16*)(ws + 28 * MB);
  u16* wpb = (u16*)(ws + 30 * MB);
  u16* Qb  = (u16*)(ws + 32 * MB);
  u16* Kb  = (u16*)(ws + 40 * MB);
  u16* Vb  = (u16*)(ws + 48 * MB);
  u16* Vtb = (u16*)(ws + 56 * MB);
  u16* Ob  = (u16*)(ws + 0 * MB);  // attn output over qb (dead after projections)

  const int nAct = BB * SS * DD;  // 4M
  const int nW = DD * DD;         // 1M

  cvt_all<<<dim3(16384), dim3(256), 0, stream>>>(
      queries, keys, values, Wq, Wk, Wv, Wp,
      qb, kb, vb, wqb, wkb, wvb, wpb);

  gemm_bt<u16><<<dim3(8, 32, 3), dim3(256), 0, stream>>>(
      qb, wqb, Qb, DD, DD, (size_t)nAct, (size_t)nW, (size_t)nAct);

  transpose_v<<<dim3(16, 16, 4), dim3(256), 0, stream>>>(Vb, Vtb);

  attn_kernel<<<dim3(8, 16, 4), dim3(256), 0, stream>>>(Qb, Kb, Vtb, bias, Ob);

  gemm_bt<float><<<dim3(8, 32, 1), dim3(256), 0, stream>>>(
      Ob, wpb, out, DD, DD, 0, 0, 0);
}